// Round 21
// baseline (92.214 us; speedup 1.0000x reference)
//
#include <hip/hip_runtime.h>
#include <math.h>

typedef _Float16 f16;
typedef _Float16 f16x2 __attribute__((ext_vector_type(2)));
typedef _Float16 f16x8 __attribute__((ext_vector_type(8)));
typedef short short8 __attribute__((ext_vector_type(8)));
typedef float f32x4 __attribute__((ext_vector_type(4)));

#define NROWS (8 * 2048 * 16)   // B*S*G rows of D=64
#define BLOCK 512
#define WAVES 8
#define NITER 8                 // one block/CU -> staging paid once (r17)
#define GRID 256
#define TAU2 4.4e-4f            // rescue threshold in log2 units (=3e-4 nats)
#define LOG2E 1.4426950408889634f
#define MEXP 6.0f               // fixed exp2 offset (r18-validated)
#define EXP2F(x) __builtin_amdgcn_exp2f(x)   // glibc reserves __exp2f (r9)

__device__ __forceinline__ short f2bf(float f) {
    unsigned u = __builtin_bit_cast(unsigned, f);
    return (short)((u + 0x7fffu + ((u >> 16) & 1u)) >> 16);
}
__device__ __forceinline__ float bf2f(short h) {
    return __builtin_bit_cast(float, ((unsigned)(unsigned short)h) << 16);
}
__device__ __forceinline__ f16x2 pkrtz(float a, float b) {
    return __builtin_bit_cast(f16x2, __builtin_amdgcn_cvt_pkrtz(a, b));
}
// async global->LDS, 16B/lane, zero VGPR round-trip. LDS dest is
// wave-uniform base + lane*16 (HW); global src is per-lane.
__device__ __forceinline__ void gload_lds16(const void* g, void* l) {
    __builtin_amdgcn_global_load_lds(
        (const __attribute__((address_space(1))) unsigned int*)g,
        (__attribute__((address_space(3))) unsigned int*)l, 16, 0, 0);
}

// One half (160 codes = 10 tiles = 5 pairs): acc[10] keeps liveness under the
// immovable 128-VGPR budget (r4-r13 law). 2-limb bf16 W (rescue rare, r16 law).
// All hot operands from LDS (r15 law). PV: f16 K=32 virtual-k pairing (r20):
// P-frag = lane's own 8 acc values, 20 MFMAs/half, zero shuffles.
template <int HB>
__device__ __forceinline__ void half_pass(
    const short* __restrict__ Wh, const short* __restrict__ Wl,
    const f16* __restrict__ CVp, const float* __restrict__ bs,
    const short8 (&xh)[2], const short8 (&xl)[2],
    int l15, int lg, int wb0, int wb1, int bsb, int cvb,
    f32x4 (&cv)[4], float& sum_run,
    float& m1o, float& m2o, int& i1o, int& c0, int& c1, int& c2)
{
    // ---- logits (log2-scaled): acc = b2 + wh*xh + wh*xl + wl*xh ----
    f32x4 acc[10];
    __builtin_amdgcn_s_setprio(1);
    #pragma unroll
    for (int nt = 0; nt < 10; ++nt) {
        const int ntg = HB / 16 + nt;
        acc[nt] = *(const f32x4*)&bs[ntg * 16 + bsb];   // bias C-init
        short8 whf0 = *(const short8*)&Wh[ntg * 1024 + wb0];
        short8 wlf0 = *(const short8*)&Wl[ntg * 1024 + wb0];
        acc[nt] = __builtin_amdgcn_mfma_f32_16x16x32_bf16(whf0, xl[0], acc[nt], 0, 0, 0);
        acc[nt] = __builtin_amdgcn_mfma_f32_16x16x32_bf16(wlf0, xh[0], acc[nt], 0, 0, 0);
        acc[nt] = __builtin_amdgcn_mfma_f32_16x16x32_bf16(whf0, xh[0], acc[nt], 0, 0, 0);
        short8 whf1 = *(const short8*)&Wh[ntg * 1024 + wb1];
        short8 wlf1 = *(const short8*)&Wl[ntg * 1024 + wb1];
        acc[nt] = __builtin_amdgcn_mfma_f32_16x16x32_bf16(whf1, xl[1], acc[nt], 0, 0, 0);
        acc[nt] = __builtin_amdgcn_mfma_f32_16x16x32_bf16(wlf1, xh[1], acc[nt], 0, 0, 0);
        acc[nt] = __builtin_amdgcn_mfma_f32_16x16x32_bf16(whf1, xh[1], acc[nt], 0, 0, 0);
    }
    __builtin_amdgcn_s_setprio(0);

    // ---- top-2 / argmax: two independent chains (half dep depth) ----
    float m1a = -INFINITY, m2a = -INFINITY, m1b = -INFINITY, m2b = -INFINITY;
    int i1a = HB, i1b = HB + 80;
    #pragma unroll
    for (int nt = 0; nt < 5; ++nt) {
        #pragma unroll
        for (int r = 0; r < 4; ++r) {
            float va = acc[nt][r];
            m2a = fmaxf(m2a, fminf(m1a, va));
            if (va > m1a) { m1a = va; i1a = HB + nt * 16 + lg * 4 + r; }
            float vb = acc[nt + 5][r];
            m2b = fmaxf(m2b, fminf(m1b, vb));
            if (vb > m1b) { m1b = vb; i1b = HB + (nt + 5) * 16 + lg * 4 + r; }
        }
    }

    // ---- fused exp2(acc-M) + paired PV (5 pairs, K=32, lane-local P) ----
    float sA = 0.f, sB = 0.f, sC = 0.f, sD = 0.f;
    #pragma unroll
    for (int lp = 0; lp < 5; ++lp) {
        const int pg = HB / 32 + lp;
        float q0 = EXP2F(acc[lp * 2][0] - MEXP);
        float q1 = EXP2F(acc[lp * 2][1] - MEXP);
        float q2 = EXP2F(acc[lp * 2][2] - MEXP);
        float q3 = EXP2F(acc[lp * 2][3] - MEXP);
        float q4 = EXP2F(acc[lp * 2 + 1][0] - MEXP);
        float q5 = EXP2F(acc[lp * 2 + 1][1] - MEXP);
        float q6 = EXP2F(acc[lp * 2 + 1][2] - MEXP);
        float q7 = EXP2F(acc[lp * 2 + 1][3] - MEXP);
        sA += q0 + q4; sB += q1 + q5; sC += q2 + q6; sD += q3 + q7;
        f16x2 a01 = pkrtz(q0, q1), a23 = pkrtz(q2, q3);
        f16x2 a45 = pkrtz(q4, q5), a67 = pkrtz(q6, q7);
        f16x8 pf = {a01[0], a01[1], a23[0], a23[1],
                    a45[0], a45[1], a67[0], a67[1]};
        #pragma unroll
        for (int dt = 0; dt < 4; ++dt) {
            f16x8 cf = *(const f16x8*)&CVp[(pg * 4 + dt) * 512 + cvb];
            cv[dt] = __builtin_amdgcn_mfma_f32_16x16x32_f16(cf, pf, cv[dt], 0, 0, 0);
        }
    }
    sum_run += (sA + sB) + (sC + sD);

    // ---- cross-lane reduce m1/m2/i1 ----
    float m2 = fmaxf(fmaxf(m2a, m2b), fminf(m1a, m1b));
    float m1 = m1a;
    int i1 = i1a;
    if (m1b > m1) { m1 = m1b; i1 = i1b; }   // tie -> chain a (lower codes)
    #pragma unroll
    for (int dx = 16; dx <= 32; dx <<= 1) {
        float mo = __shfl_xor(m1, dx, 64);
        int io = __shfl_xor(i1, dx, 64);
        float m2x = __shfl_xor(m2, dx, 64);
        m2 = fmaxf(fmaxf(m2, m2x), fminf(m1, mo));
        if (mo > m1 || (mo == m1 && io < i1)) { m1 = mo; i1 = io; }
    }

    // ---- candidate collection, gated on per-half near-tie ----
    c0 = -1; c1 = -1; c2 = -1;
    if (m1 - m2 < TAU2) {
        const float thr = m1 - TAU2;
        #pragma unroll
        for (int nt = 0; nt < 10; ++nt) {
            #pragma unroll
            for (int r = 0; r < 4; ++r) {
                if (acc[nt][r] >= thr) {
                    int c = HB + nt * 16 + lg * 4 + r;
                    if (c0 < 0) c0 = c;
                    else if (c1 < 0) c1 = c;
                    else if (c2 < 0) c2 = c;
                }
            }
        }
    }
    m1o = m1; m2o = m2; i1o = i1;
}

__global__ __launch_bounds__(BLOCK) void vq_mfma(
    const float* __restrict__ inputs,   // [262144][64]
    const int* __restrict__ mask,       // [16384]
    const float* __restrict__ Wcb,      // [64][320] raw (staging + rescue)
    const float* __restrict__ bcb,      // [320] raw (rescue)
    const float* __restrict__ codevec,  // [320][64]
    float* __restrict__ out_cv,         // [262144][64]
    float* __restrict__ out_cw)         // [262144] as float
{
    // W^T bf16 limbs (log2e-scaled), swizzled: slot' = slot ^ (n&7)
    __shared__ __align__(16) short Wh[320 * 64];
    __shared__ __align__(16) short Wl[320 * 64];
    // CV paired-f16 (r20): block (pair*4+dt) of [16 rows][32 virtual-k]
    __shared__ __align__(16) f16 CVp[20480];
    __shared__ __align__(16) float bs[320];    // bias * log2e
    // per-wave x prefetch tile: 16 rows x 64 f32, chunk-swizzled.
    // LDS total 156928 B <= 160 KB; per-wave private -> no barriers.
    __shared__ __align__(16) float xs[WAVES][1024];

    const int tid = threadIdx.x;

    for (int e = tid; e < 64 * 320; e += BLOCK) {
        int d = e / 320, n = e - d * 320;      // coalesced Wcb read
        float w = Wcb[e] * LOG2E;
        short wh = f2bf(w);
        short wl = f2bf(w - bf2f(wh));
        int s = d >> 3;
        int idx = n * 64 + (((s ^ n) & 7) << 3) + (d & 7);
        Wh[idx] = wh;
        Wl[idx] = wl;
    }
    for (int e = tid; e < 320 * 64; e += BLOCK) {
        int c = e >> 6, d = e & 63;            // codevec [320][64] k-major
        int p = c >> 5, tp = (c >> 4) & 1, tc = c & 15;
        int lgc = tc >> 2, r = tc & 3;
        int ee = (tp << 2) | r;
        int dt = d >> 4, m = d & 15;
        CVp[(p * 4 + dt) * 512 + m * 32 + (((lgc ^ (m >> 1)) & 3) << 3) + ee] =
            (f16)codevec[e];
    }
    for (int e = tid; e < 320; e += BLOCK) bs[e] = bcb[e] * LOG2E;
    __syncthreads();

    const int wid = tid >> 6;
    const int lane = tid & 63;
    const int l15 = lane & 15;          // C column = data row
    const int lg = lane >> 4;           // frag k-group 0..3
    const int l7 = l15 & 7;
    const int u = blockIdx.x * WAVES + wid;   // 0..2047

    // it-invariant LDS element bases
    const int wb0 = l15 * 64 + (((lg ^ l7) & 7) << 3);          // kc=0
    const int wb1 = l15 * 64 + ((((4 + lg) ^ l7) & 7) << 3);    // kc=1
    const int bsb = lg * 4;
    const int cvb = l15 * 32 + (((lg ^ (l15 >> 1)) & 3) << 3);  // paired CV

    char* xsw = (char*)&xs[wid][0];
    // per-lane swizzled global offset for the prefetch: LDS gets linear
    // (i*1024 + lane*16); source chunk = lds_chunk ^ (row&7) so that LDS
    // holds row r with its 16B chunks XOR-permuted (bank-balanced reads).
    int goff[4];
    #pragma unroll
    for (int i = 0; i < 4; ++i) {
        int o = i * 1024 + lane * 16;
        int r = o >> 8;
        int ch = ((o >> 4) & 15) ^ (r & 7);
        goff[i] = r * 256 + ch * 16;
    }

    // prologue: prefetch x tile for it=0
    {
        const char* src = (const char*)(inputs + (size_t)u * (NITER * 16) * 64);
        #pragma unroll
        for (int i = 0; i < 4; ++i)
            gload_lds16(src + goff[i], xsw + i * 1024);
    }

    #pragma unroll 1
    for (int it = 0; it < NITER; ++it) {
        const int row0 = u * (NITER * 16) + it * 16;
        const float* xrow = inputs + (size_t)(row0 + l15) * 64;   // rescue path

        // ---- wait prefetched x, read (swizzled) + limb-convert ----
        asm volatile("s_waitcnt vmcnt(0)" ::: "memory");
        __builtin_amdgcn_sched_barrier(0);
        short8 xh[2], xl[2];
        #pragma unroll
        for (int kc = 0; kc < 2; ++kc) {
            int ca = (kc * 8 + lg * 2) ^ l7;
            int cb = (kc * 8 + lg * 2 + 1) ^ l7;
            float4 a = *(const float4*)&xs[wid][l15 * 64 + (ca << 2)];
            float4 b = *(const float4*)&xs[wid][l15 * 64 + (cb << 2)];
            float xv[8] = {a.x, a.y, a.z, a.w, b.x, b.y, b.z, b.w};
            short8 h, l;
            #pragma unroll
            for (int e = 0; e < 8; ++e) {
                short hh = f2bf(xv[e]);
                h[e] = hh;
                l[e] = f2bf(xv[e] - bf2f(hh));
            }
            xh[kc] = h;
            xl[kc] = l;
        }
        // reads complete -> safe to overwrite; issue next-iter prefetch NOW
        asm volatile("s_waitcnt lgkmcnt(0)" ::: "memory");
        __builtin_amdgcn_sched_barrier(0);
        if (it + 1 < NITER) {
            const char* src = (const char*)(inputs +
                (size_t)(u * (NITER * 16) + (it + 1) * 16) * 64);
            #pragma unroll
            for (int i = 0; i < 4; ++i)
                gload_lds16(src + goff[i], xsw + i * 1024);
        }

        f32x4 cv[4];
        #pragma unroll
        for (int dt = 0; dt < 4; ++dt) cv[dt] = (f32x4){0.f, 0.f, 0.f, 0.f};
        float sum_run = 0.f;
        float m1A, m2A, m1B, m2B;
        int i1A, i1B, cA0, cA1, cA2, cB0, cB1, cB2;

        half_pass<0>(Wh, Wl, CVp, bs, xh, xl, l15, lg,
                     wb0, wb1, bsb, cvb,
                     cv, sum_run, m1A, m2A, i1A, cA0, cA1, cA2);
        half_pass<160>(Wh, Wl, CVp, bs, xh, xl, l15, lg,
                       wb0, wb1, bsb, cvb,
                       cv, sum_run, m1B, m2B, i1B, cB0, cB1, cB2);

        // ---- merge halves: global top-2 / argmax ----
        float m1 = m1A;
        int i1 = i1A;
        float m2 = fmaxf(fmaxf(m2A, m2B), fminf(m1A, m1B));
        if (m1B > m1) { m1 = m1B; i1 = i1B; }   // tie -> half A (smaller index)

        float sum = sum_run;
        sum += __shfl_xor(sum, 16, 64);
        sum += __shfl_xor(sum, 32, 64);

        // ---- exact-argmax rescue for near-ties (raw f32, nat units) ----
        // fmaf order (bias first, d ascending) preserved from r3-r20.
        const int mk = mask[u * NITER + it];   // wave-uniform
        int cw = i1;
        const bool flag = mk && (m1 - m2 < TAU2);
        if (__any(flag)) {
            float bv = -INFINITY;
            int bi = 0x7fffffff;
            #pragma unroll 1
            for (int t = 0; t < 8; ++t) {
                int c = (t == 0) ? i1A : (t == 1) ? i1B :
                        (t == 2) ? cA0 : (t == 3) ? cA1 : (t == 4) ? cA2 :
                        (t == 5) ? cB0 : (t == 6) ? cB1 : cB2;
                if (!flag) c = -1;
                if (__any(c >= 0)) {
                    if (c >= 0) {
                        float sacc = bcb[c];
                        #pragma unroll 4
                        for (int q = 0; q < 16; ++q) {
                            float4 xv4 = *(const float4*)(xrow + q * 4);
                            sacc = fmaf(xv4.x, Wcb[(q * 4 + 0) * 320 + c], sacc);
                            sacc = fmaf(xv4.y, Wcb[(q * 4 + 1) * 320 + c], sacc);
                            sacc = fmaf(xv4.z, Wcb[(q * 4 + 2) * 320 + c], sacc);
                            sacc = fmaf(xv4.w, Wcb[(q * 4 + 3) * 320 + c], sacc);
                        }
                        if (sacc > bv || (sacc == bv && c < bi)) { bv = sacc; bi = c; }
                    }
                }
            }
            #pragma unroll
            for (int dx = 16; dx <= 32; dx <<= 1) {
                float vo = __shfl_xor(bv, dx, 64);
                int io = __shfl_xor(bi, dx, 64);
                if (vo > bv || (vo == bv && io < bi)) { bv = vo; bi = io; }
            }
            if (flag) cw = bi;
        }

        // ---- epilogue: mask, normalize, store ----
        const float inv = mk ? (1.0f / sum) : 0.0f;
        float* orow = out_cv + (size_t)(row0 + l15) * 64;
        #pragma unroll
        for (int dt = 0; dt < 4; ++dt) {
            f32x4 v;
            v[0] = cv[dt][0] * inv;
            v[1] = cv[dt][1] * inv;
            v[2] = cv[dt][2] * inv;
            v[3] = cv[dt][3] * inv;
            *(f32x4*)(orow + dt * 16 + lg * 4) = v;
        }
        if (lg == 0) out_cw[row0 + l15] = mk ? (float)cw : 0.0f;
    }
}

extern "C" void kernel_launch(void* const* d_in, const int* in_sizes, int n_in,
                              void* d_out, int out_size, void* d_ws, size_t ws_size,
                              hipStream_t stream) {
    const float* inputs  = (const float*)d_in[0];
    const int*   mask    = (const int*)d_in[1];
    const float* Wcb     = (const float*)d_in[2];
    const float* bcb     = (const float*)d_in[3];
    const float* codevec = (const float*)d_in[4];

    float* out_cv = (float*)d_out;
    float* out_cw = out_cv + (size_t)NROWS * 64;

    vq_mfma<<<GRID, BLOCK, 0, stream>>>(inputs, mask, Wcb, bcb, codevec,
                                        out_cv, out_cw);
}

// Round 22
// 82.006 us; speedup vs baseline: 1.1245x; 1.1245x over previous
//
#include <hip/hip_runtime.h>
#include <math.h>

typedef _Float16 f16;
typedef _Float16 f16x2 __attribute__((ext_vector_type(2)));
typedef _Float16 f16x8 __attribute__((ext_vector_type(8)));
typedef __bf16 bf16x8 __attribute__((ext_vector_type(8)));
typedef short short8 __attribute__((ext_vector_type(8)));
typedef float f32x4 __attribute__((ext_vector_type(4)));

#define NROWS (8 * 2048 * 16)   // B*S*G rows of D=64
#define BLOCK 512
#define WAVES 8
#define NITER 8                 // one block/CU -> staging paid once (r17)
#define GRID 256
#define TAU2 4.4e-4f            // rescue threshold in log2 units (=3e-4 nats)
#define LOG2E 1.4426950408889634f
#define MEXP 6.0f               // fixed exp2 offset (r18-validated)
#define EXP2F(x) __builtin_amdgcn_exp2f(x)   // glibc reserves __exp2f (r9)

__device__ __forceinline__ short f2bf(float f) {
    unsigned u = __builtin_bit_cast(unsigned, f);
    return (short)((u + 0x7fffu + ((u >> 16) & 1u)) >> 16);
}
__device__ __forceinline__ float bf2f(short h) {
    return __builtin_bit_cast(float, ((unsigned)(unsigned short)h) << 16);
}
__device__ __forceinline__ f16x2 pkrtz(float a, float b) {
    return __builtin_bit_cast(f16x2, __builtin_amdgcn_cvt_pkrtz(a, b));
}

// One half (160 codes = 10 tiles = 5 pairs): acc[10] keeps liveness under the
// immovable 128-VGPR budget (r4-r13 law). 2-limb bf16 W (rescue rare, r16 law).
// All hot operands from LDS (r15 law). PV: f16 K=32 virtual-k pairing (r20).
// Softmax sum via all-ones-A MFMA: K spans all 4 lane-groups -> the MFMA does
// the cross-lane reduce for free on the idle matrix pipe (replaces 80 v_add
// + 2 shuffles per iter).
template <int HB>
__device__ __forceinline__ void half_pass(
    const short* __restrict__ Wh, const short* __restrict__ Wl,
    const f16* __restrict__ CVp, const float* __restrict__ bs,
    const short8 (&xh)[2], const short8 (&xl)[2],
    int l15, int lg, int wb0, int wb1, int bsb, int cvb,
    f32x4 (&cv)[4], f32x4& sacc,
    float& m1o, float& m2o, int& i1o, int& c0, int& c1, int& c2)
{
    // ---- logits (log2-scaled): acc = b2 + wh*xh + wh*xl + wl*xh ----
    f32x4 acc[10];
    __builtin_amdgcn_s_setprio(1);
    #pragma unroll
    for (int nt = 0; nt < 10; ++nt) {
        const int ntg = HB / 16 + nt;
        acc[nt] = *(const f32x4*)&bs[ntg * 16 + bsb];   // bias C-init
        short8 whf0 = *(const short8*)&Wh[ntg * 1024 + wb0];
        short8 wlf0 = *(const short8*)&Wl[ntg * 1024 + wb0];
        acc[nt] = __builtin_amdgcn_mfma_f32_16x16x32_bf16(whf0, xl[0], acc[nt], 0, 0, 0);
        acc[nt] = __builtin_amdgcn_mfma_f32_16x16x32_bf16(wlf0, xh[0], acc[nt], 0, 0, 0);
        acc[nt] = __builtin_amdgcn_mfma_f32_16x16x32_bf16(whf0, xh[0], acc[nt], 0, 0, 0);
        short8 whf1 = *(const short8*)&Wh[ntg * 1024 + wb1];
        short8 wlf1 = *(const short8*)&Wl[ntg * 1024 + wb1];
        acc[nt] = __builtin_amdgcn_mfma_f32_16x16x32_bf16(whf1, xl[1], acc[nt], 0, 0, 0);
        acc[nt] = __builtin_amdgcn_mfma_f32_16x16x32_bf16(wlf1, xh[1], acc[nt], 0, 0, 0);
        acc[nt] = __builtin_amdgcn_mfma_f32_16x16x32_bf16(whf1, xh[1], acc[nt], 0, 0, 0);
    }
    __builtin_amdgcn_s_setprio(0);

    // ---- top-2 / argmax: two independent chains (half dep depth) ----
    float m1a = -INFINITY, m2a = -INFINITY, m1b = -INFINITY, m2b = -INFINITY;
    int i1a = HB, i1b = HB + 80;
    #pragma unroll
    for (int nt = 0; nt < 5; ++nt) {
        #pragma unroll
        for (int r = 0; r < 4; ++r) {
            float va = acc[nt][r];
            m2a = fmaxf(m2a, fminf(m1a, va));
            if (va > m1a) { m1a = va; i1a = HB + nt * 16 + lg * 4 + r; }
            float vb = acc[nt + 5][r];
            m2b = fmaxf(m2b, fminf(m1b, vb));
            if (vb > m1b) { m1b = vb; i1b = HB + (nt + 5) * 16 + lg * 4 + r; }
        }
    }

    // ---- fused exp2(acc-M) + paired PV (5 pairs, K=32, lane-local P) ----
    const f16x8 ones = {f16(1), f16(1), f16(1), f16(1),
                        f16(1), f16(1), f16(1), f16(1)};
    #pragma unroll
    for (int lp = 0; lp < 5; ++lp) {
        const int pg = HB / 32 + lp;
        float q0 = EXP2F(acc[lp * 2][0] - MEXP);
        float q1 = EXP2F(acc[lp * 2][1] - MEXP);
        float q2 = EXP2F(acc[lp * 2][2] - MEXP);
        float q3 = EXP2F(acc[lp * 2][3] - MEXP);
        float q4 = EXP2F(acc[lp * 2 + 1][0] - MEXP);
        float q5 = EXP2F(acc[lp * 2 + 1][1] - MEXP);
        float q6 = EXP2F(acc[lp * 2 + 1][2] - MEXP);
        float q7 = EXP2F(acc[lp * 2 + 1][3] - MEXP);
        f16x2 a01 = pkrtz(q0, q1), a23 = pkrtz(q2, q3);
        f16x2 a45 = pkrtz(q4, q5), a67 = pkrtz(q6, q7);
        f16x8 pf = {a01[0], a01[1], a23[0], a23[1],
                    a45[0], a45[1], a67[0], a67[1]};
        #pragma unroll
        for (int dt = 0; dt < 4; ++dt) {
            f16x8 cf = *(const f16x8*)&CVp[(pg * 4 + dt) * 512 + cvb];
            cv[dt] = __builtin_amdgcn_mfma_f32_16x16x32_f16(cf, pf, cv[dt], 0, 0, 0);
        }
        // sum over this pair's 32 codes (all lanes' k) on the MFMA pipe
        sacc = __builtin_amdgcn_mfma_f32_16x16x32_f16(ones, pf, sacc, 0, 0, 0);
    }

    // ---- cross-lane reduce m1/m2/i1 ----
    float m2 = fmaxf(fmaxf(m2a, m2b), fminf(m1a, m1b));
    float m1 = m1a;
    int i1 = i1a;
    if (m1b > m1) { m1 = m1b; i1 = i1b; }   // tie -> chain a (lower codes)
    #pragma unroll
    for (int dx = 16; dx <= 32; dx <<= 1) {
        float mo = __shfl_xor(m1, dx, 64);
        int io = __shfl_xor(i1, dx, 64);
        float m2x = __shfl_xor(m2, dx, 64);
        m2 = fmaxf(fmaxf(m2, m2x), fminf(m1, mo));
        if (mo > m1 || (mo == m1 && io < i1)) { m1 = mo; i1 = io; }
    }

    // ---- candidate collection, gated on per-half near-tie ----
    c0 = -1; c1 = -1; c2 = -1;
    if (m1 - m2 < TAU2) {
        const float thr = m1 - TAU2;
        #pragma unroll
        for (int nt = 0; nt < 10; ++nt) {
            #pragma unroll
            for (int r = 0; r < 4; ++r) {
                if (acc[nt][r] >= thr) {
                    int c = HB + nt * 16 + lg * 4 + r;
                    if (c0 < 0) c0 = c;
                    else if (c1 < 0) c1 = c;
                    else if (c2 < 0) c2 = c;
                }
            }
        }
    }
    m1o = m1; m2o = m2; i1o = i1;
}

__global__ __launch_bounds__(BLOCK) void vq_mfma(
    const float* __restrict__ inputs,   // [262144][64]
    const int* __restrict__ mask,       // [16384]
    const float* __restrict__ Wcb,      // [64][320] raw (staging + rescue)
    const float* __restrict__ bcb,      // [320] raw (rescue)
    const float* __restrict__ codevec,  // [320][64]
    float* __restrict__ out_cv,         // [262144][64]
    float* __restrict__ out_cw)         // [262144] as float
{
    // W^T bf16 limbs (log2e-scaled), swizzled: slot' = slot ^ (n&7)
    __shared__ __align__(16) short Wh[320 * 64];
    __shared__ __align__(16) short Wl[320 * 64];
    // CV paired-f16 (r20): block (pair*4+dt) of [16 rows][32 virtual-k]
    __shared__ __align__(16) f16 CVp[20480];
    __shared__ __align__(16) float bs[320];    // bias * log2e

    const int tid = threadIdx.x;

    for (int e = tid; e < 64 * 320; e += BLOCK) {
        int d = e / 320, n = e - d * 320;      // coalesced Wcb read
        float w = Wcb[e] * LOG2E;
        short wh = f2bf(w);
        short wl = f2bf(w - bf2f(wh));
        int s = d >> 3;
        int idx = n * 64 + (((s ^ n) & 7) << 3) + (d & 7);
        Wh[idx] = wh;
        Wl[idx] = wl;
    }
    for (int e = tid; e < 320 * 64; e += BLOCK) {
        int c = e >> 6, d = e & 63;            // codevec [320][64] k-major
        int p = c >> 5, tp = (c >> 4) & 1, tc = c & 15;
        int lgc = tc >> 2, r = tc & 3;
        int ee = (tp << 2) | r;
        int dt = d >> 4, m = d & 15;
        CVp[(p * 4 + dt) * 512 + m * 32 + (((lgc ^ (m >> 1)) & 3) << 3) + ee] =
            (f16)codevec[e];
    }
    for (int e = tid; e < 320; e += BLOCK) bs[e] = bcb[e] * LOG2E;
    __syncthreads();

    const int wid = tid >> 6;
    const int lane = tid & 63;
    const int l15 = lane & 15;          // C column = data row
    const int lg = lane >> 4;           // frag k-group 0..3
    const int l7 = l15 & 7;
    const int u = blockIdx.x * WAVES + wid;   // 0..2047

    // it-invariant LDS element bases
    const int wb0 = l15 * 64 + (((lg ^ l7) & 7) << 3);          // kc=0
    const int wb1 = l15 * 64 + ((((4 + lg) ^ l7) & 7) << 3);    // kc=1
    const int bsb = lg * 4;
    const int cvb = l15 * 32 + (((lg ^ (l15 >> 1)) & 3) << 3);  // paired CV

    #pragma unroll 1
    for (int it = 0; it < NITER; ++it) {
        const int row0 = u * (NITER * 16) + it * 16;
        const float* xrow = inputs + (size_t)(row0 + l15) * 64;

        // ---- x B-frags, 2 bf16 limbs via native casts (compiler emits
        // packed v_cvt_pk_bf16_f32; RNE == f2bf, bit-identical) ----
        short8 xh[2], xl[2];
        #pragma unroll
        for (int kc = 0; kc < 2; ++kc) {
            float4 a = *(const float4*)(xrow + kc * 32 + lg * 8);
            float4 b = *(const float4*)(xrow + kc * 32 + lg * 8 + 4);
            float xv[8] = {a.x, a.y, a.z, a.w, b.x, b.y, b.z, b.w};
            bf16x8 h, l;
            #pragma unroll
            for (int e = 0; e < 8; ++e) {
                __bf16 hh = (__bf16)xv[e];
                h[e] = hh;
                l[e] = (__bf16)(xv[e] - (float)hh);
            }
            xh[kc] = __builtin_bit_cast(short8, h);
            xl[kc] = __builtin_bit_cast(short8, l);
        }

        f32x4 cv[4];
        #pragma unroll
        for (int dt = 0; dt < 4; ++dt) cv[dt] = (f32x4){0.f, 0.f, 0.f, 0.f};
        f32x4 sacc = (f32x4){0.f, 0.f, 0.f, 0.f};
        float m1A, m2A, m1B, m2B;
        int i1A, i1B, cA0, cA1, cA2, cB0, cB1, cB2;

        half_pass<0>(Wh, Wl, CVp, bs, xh, xl, l15, lg,
                     wb0, wb1, bsb, cvb,
                     cv, sacc, m1A, m2A, i1A, cA0, cA1, cA2);
        half_pass<160>(Wh, Wl, CVp, bs, xh, xl, l15, lg,
                       wb0, wb1, bsb, cvb,
                       cv, sacc, m1B, m2B, i1B, cB0, cB1, cB2);

        // ---- merge halves: global top-2 / argmax ----
        float m1 = m1A;
        int i1 = i1A;
        float m2 = fmaxf(fmaxf(m2A, m2B), fminf(m1A, m1B));
        if (m1B > m1) { m1 = m1B; i1 = i1B; }   // tie -> half A (smaller index)

        const float sum = sacc[0];   // MFMA K-reduce spans all 4 lane-groups

        // ---- exact-argmax rescue for near-ties (raw f32, nat units) ----
        // fmaf order (bias first, d ascending) preserved from r3-r21.
        const int mk = mask[u * NITER + it];   // wave-uniform
        int cw = i1;
        const bool flag = mk && (m1 - m2 < TAU2);
        if (__any(flag)) {
            float bv = -INFINITY;
            int bi = 0x7fffffff;
            #pragma unroll 1
            for (int t = 0; t < 8; ++t) {
                int c = (t == 0) ? i1A : (t == 1) ? i1B :
                        (t == 2) ? cA0 : (t == 3) ? cA1 : (t == 4) ? cA2 :
                        (t == 5) ? cB0 : (t == 6) ? cB1 : cB2;
                if (!flag) c = -1;
                if (__any(c >= 0)) {
                    if (c >= 0) {
                        float sacc2 = bcb[c];
                        #pragma unroll 4
                        for (int q = 0; q < 16; ++q) {
                            float4 xv4 = *(const float4*)(xrow + q * 4);
                            sacc2 = fmaf(xv4.x, Wcb[(q * 4 + 0) * 320 + c], sacc2);
                            sacc2 = fmaf(xv4.y, Wcb[(q * 4 + 1) * 320 + c], sacc2);
                            sacc2 = fmaf(xv4.z, Wcb[(q * 4 + 2) * 320 + c], sacc2);
                            sacc2 = fmaf(xv4.w, Wcb[(q * 4 + 3) * 320 + c], sacc2);
                        }
                        if (sacc2 > bv || (sacc2 == bv && c < bi)) { bv = sacc2; bi = c; }
                    }
                }
            }
            #pragma unroll
            for (int dx = 16; dx <= 32; dx <<= 1) {
                float vo = __shfl_xor(bv, dx, 64);
                int io = __shfl_xor(bi, dx, 64);
                if (vo > bv || (vo == bv && io < bi)) { bv = vo; bi = io; }
            }
            if (flag) cw = bi;
        }

        // ---- epilogue: mask, normalize, store ----
        const float inv = mk ? (1.0f / sum) : 0.0f;
        float* orow = out_cv + (size_t)(row0 + l15) * 64;
        #pragma unroll
        for (int dt = 0; dt < 4; ++dt) {
            f32x4 v;
            v[0] = cv[dt][0] * inv;
            v[1] = cv[dt][1] * inv;
            v[2] = cv[dt][2] * inv;
            v[3] = cv[dt][3] * inv;
            *(f32x4*)(orow + dt * 16 + lg * 4) = v;
        }
        if (lg == 0) out_cw[row0 + l15] = mk ? (float)cw : 0.0f;
    }
}

extern "C" void kernel_launch(void* const* d_in, const int* in_sizes, int n_in,
                              void* d_out, int out_size, void* d_ws, size_t ws_size,
                              hipStream_t stream) {
    const float* inputs  = (const float*)d_in[0];
    const int*   mask    = (const int*)d_in[1];
    const float* Wcb     = (const float*)d_in[2];
    const float* bcb     = (const float*)d_in[3];
    const float* codevec = (const float*)d_in[4];

    float* out_cv = (float*)d_out;
    float* out_cw = out_cv + (size_t)NROWS * 64;

    vq_mfma<<<GRID, BLOCK, 0, stream>>>(inputs, mask, Wcb, bcb, codevec,
                                        out_cv, out_cw);
}

// Round 23
// 80.930 us; speedup vs baseline: 1.1394x; 1.0133x over previous
//
#include <hip/hip_runtime.h>
#include <math.h>

typedef _Float16 f16;
typedef _Float16 f16x2 __attribute__((ext_vector_type(2)));
typedef _Float16 f16x8 __attribute__((ext_vector_type(8)));
typedef __bf16 bf16x8 __attribute__((ext_vector_type(8)));
typedef short short8 __attribute__((ext_vector_type(8)));
typedef float f32x4 __attribute__((ext_vector_type(4)));

#define NROWS (8 * 2048 * 16)   // B*S*G rows of D=64
#define BLOCK 512
#define WAVES 8
#define NITER 8                 // one block/CU -> staging paid once (r17)
#define GRID 256
#define TAU2 4.4e-4f            // rescue threshold in log2 units (=3e-4 nats)
#define LOG2E 1.4426950408889634f
#define MEXP 6.0f               // fixed exp2 offset (r18-validated)
#define EXP2F(x) __builtin_amdgcn_exp2f(x)   // glibc reserves __exp2f (r9)

__device__ __forceinline__ short f2bf(float f) {
    unsigned u = __builtin_bit_cast(unsigned, f);
    return (short)((u + 0x7fffu + ((u >> 16) & 1u)) >> 16);
}
__device__ __forceinline__ float bf2f(short h) {
    return __builtin_bit_cast(float, ((unsigned)(unsigned short)h) << 16);
}
__device__ __forceinline__ f16x2 pkrtz(float a, float b) {
    return __builtin_bit_cast(f16x2, __builtin_amdgcn_cvt_pkrtz(a, b));
}

// One half (160 codes = 10 tiles = 5 pairs): acc[10] keeps liveness under the
// immovable 128-VGPR budget (r4-r13 law). 2-limb bf16 W (rescue rare, r16 law).
// All hot operands from LDS (r15 law). PV: f16 K=32 virtual-k pairing (r20).
// Softmax sum via all-ones-A MFMA (r22): cross-lane reduce free on matrix pipe.
template <int HB>
__device__ __forceinline__ void half_pass(
    const short* __restrict__ Wh, const short* __restrict__ Wl,
    const f16* __restrict__ CVp, const float* __restrict__ bs,
    const short8 (&xh)[2], const short8 (&xl)[2],
    int l15, int lg, int wb0, int wb1, int bsb, int cvb,
    f32x4 (&cv)[4], f32x4& sacc,
    float& m1o, float& m2o, int& i1o, int& c0, int& c1, int& c2)
{
    // ---- logits (log2-scaled): acc = b2 + wh*xh + wh*xl + wl*xh ----
    f32x4 acc[10];
    __builtin_amdgcn_s_setprio(1);
    #pragma unroll
    for (int nt = 0; nt < 10; ++nt) {
        const int ntg = HB / 16 + nt;
        acc[nt] = *(const f32x4*)&bs[ntg * 16 + bsb];   // bias C-init
        short8 whf0 = *(const short8*)&Wh[ntg * 1024 + wb0];
        short8 wlf0 = *(const short8*)&Wl[ntg * 1024 + wb0];
        acc[nt] = __builtin_amdgcn_mfma_f32_16x16x32_bf16(whf0, xl[0], acc[nt], 0, 0, 0);
        acc[nt] = __builtin_amdgcn_mfma_f32_16x16x32_bf16(wlf0, xh[0], acc[nt], 0, 0, 0);
        acc[nt] = __builtin_amdgcn_mfma_f32_16x16x32_bf16(whf0, xh[0], acc[nt], 0, 0, 0);
        short8 whf1 = *(const short8*)&Wh[ntg * 1024 + wb1];
        short8 wlf1 = *(const short8*)&Wl[ntg * 1024 + wb1];
        acc[nt] = __builtin_amdgcn_mfma_f32_16x16x32_bf16(whf1, xl[1], acc[nt], 0, 0, 0);
        acc[nt] = __builtin_amdgcn_mfma_f32_16x16x32_bf16(wlf1, xh[1], acc[nt], 0, 0, 0);
        acc[nt] = __builtin_amdgcn_mfma_f32_16x16x32_bf16(whf1, xh[1], acc[nt], 0, 0, 0);
    }
    __builtin_amdgcn_s_setprio(0);

    // ---- top-2 / argmax: two independent chains (half dep depth) ----
    float m1a = -INFINITY, m2a = -INFINITY, m1b = -INFINITY, m2b = -INFINITY;
    int i1a = HB, i1b = HB + 80;
    #pragma unroll
    for (int nt = 0; nt < 5; ++nt) {
        #pragma unroll
        for (int r = 0; r < 4; ++r) {
            float va = acc[nt][r];
            m2a = fmaxf(m2a, fminf(m1a, va));
            if (va > m1a) { m1a = va; i1a = HB + nt * 16 + lg * 4 + r; }
            float vb = acc[nt + 5][r];
            m2b = fmaxf(m2b, fminf(m1b, vb));
            if (vb > m1b) { m1b = vb; i1b = HB + (nt + 5) * 16 + lg * 4 + r; }
        }
    }

    // ---- fused exp2(acc-M) + paired PV (5 pairs, K=32, lane-local P) ----
    const f16x8 ones = {f16(1), f16(1), f16(1), f16(1),
                        f16(1), f16(1), f16(1), f16(1)};
    #pragma unroll
    for (int lp = 0; lp < 5; ++lp) {
        const int pg = HB / 32 + lp;
        float q0 = EXP2F(acc[lp * 2][0] - MEXP);
        float q1 = EXP2F(acc[lp * 2][1] - MEXP);
        float q2 = EXP2F(acc[lp * 2][2] - MEXP);
        float q3 = EXP2F(acc[lp * 2][3] - MEXP);
        float q4 = EXP2F(acc[lp * 2 + 1][0] - MEXP);
        float q5 = EXP2F(acc[lp * 2 + 1][1] - MEXP);
        float q6 = EXP2F(acc[lp * 2 + 1][2] - MEXP);
        float q7 = EXP2F(acc[lp * 2 + 1][3] - MEXP);
        f16x2 a01 = pkrtz(q0, q1), a23 = pkrtz(q2, q3);
        f16x2 a45 = pkrtz(q4, q5), a67 = pkrtz(q6, q7);
        f16x8 pf = {a01[0], a01[1], a23[0], a23[1],
                    a45[0], a45[1], a67[0], a67[1]};
        #pragma unroll
        for (int dt = 0; dt < 4; ++dt) {
            f16x8 cf = *(const f16x8*)&CVp[(pg * 4 + dt) * 512 + cvb];
            cv[dt] = __builtin_amdgcn_mfma_f32_16x16x32_f16(cf, pf, cv[dt], 0, 0, 0);
        }
        // sum over this pair's 32 codes (all lanes' k) on the MFMA pipe
        sacc = __builtin_amdgcn_mfma_f32_16x16x32_f16(ones, pf, sacc, 0, 0, 0);
    }

    // ---- cross-lane reduce m1/m2/i1 ----
    float m2 = fmaxf(fmaxf(m2a, m2b), fminf(m1a, m1b));
    float m1 = m1a;
    int i1 = i1a;
    if (m1b > m1) { m1 = m1b; i1 = i1b; }   // tie -> chain a (lower codes)
    #pragma unroll
    for (int dx = 16; dx <= 32; dx <<= 1) {
        float mo = __shfl_xor(m1, dx, 64);
        int io = __shfl_xor(i1, dx, 64);
        float m2x = __shfl_xor(m2, dx, 64);
        m2 = fmaxf(fmaxf(m2, m2x), fminf(m1, mo));
        if (mo > m1 || (mo == m1 && io < i1)) { m1 = mo; i1 = io; }
    }

    // ---- candidate collection, gated on per-half near-tie ----
    c0 = -1; c1 = -1; c2 = -1;
    if (m1 - m2 < TAU2) {
        const float thr = m1 - TAU2;
        #pragma unroll
        for (int nt = 0; nt < 10; ++nt) {
            #pragma unroll
            for (int r = 0; r < 4; ++r) {
                if (acc[nt][r] >= thr) {
                    int c = HB + nt * 16 + lg * 4 + r;
                    if (c0 < 0) c0 = c;
                    else if (c1 < 0) c1 = c;
                    else if (c2 < 0) c2 = c;
                }
            }
        }
    }
    m1o = m1; m2o = m2; i1o = i1;
}

__global__ __launch_bounds__(BLOCK) void vq_mfma(
    const float* __restrict__ inputs,   // [262144][64]
    const int* __restrict__ mask,       // [16384]
    const float* __restrict__ Wcb,      // [64][320] raw (staging + rescue)
    const float* __restrict__ bcb,      // [320] raw (rescue)
    const float* __restrict__ codevec,  // [320][64]
    float* __restrict__ out_cv,         // [262144][64]
    float* __restrict__ out_cw)         // [262144] as float
{
    // W^T bf16 limbs (log2e-scaled), swizzled: slot' = slot ^ (n&7)
    __shared__ __align__(16) short Wh[320 * 64];
    __shared__ __align__(16) short Wl[320 * 64];
    // CV paired-f16 (r20): block (pair*4+dt) of [16 rows][32 virtual-k]
    __shared__ __align__(16) f16 CVp[20480];
    __shared__ __align__(16) float bs[320];    // bias * log2e

    const int tid = threadIdx.x;

    for (int e = tid; e < 64 * 320; e += BLOCK) {
        int d = e / 320, n = e - d * 320;      // coalesced Wcb read
        float w = Wcb[e] * LOG2E;
        short wh = f2bf(w);
        short wl = f2bf(w - bf2f(wh));
        int s = d >> 3;
        int idx = n * 64 + (((s ^ n) & 7) << 3) + (d & 7);
        Wh[idx] = wh;
        Wl[idx] = wl;
    }
    for (int e = tid; e < 320 * 64; e += BLOCK) {
        int c = e >> 6, d = e & 63;            // codevec [320][64] k-major
        int p = c >> 5, tp = (c >> 4) & 1, tc = c & 15;
        int lgc = tc >> 2, r = tc & 3;
        int ee = (tp << 2) | r;
        int dt = d >> 4, m = d & 15;
        CVp[(p * 4 + dt) * 512 + m * 32 + (((lgc ^ (m >> 1)) & 3) << 3) + ee] =
            (f16)codevec[e];
    }
    for (int e = tid; e < 320; e += BLOCK) bs[e] = bcb[e] * LOG2E;
    __syncthreads();

    const int wid = tid >> 6;
    const int lane = tid & 63;
    const int l15 = lane & 15;          // C column = data row
    const int lg = lane >> 4;           // frag k-group 0..3
    const int l7 = l15 & 7;
    const int u = blockIdx.x * WAVES + wid;   // 0..2047

    // it-invariant LDS element bases
    const int wb0 = l15 * 64 + (((lg ^ l7) & 7) << 3);          // kc=0
    const int wb1 = l15 * 64 + ((((4 + lg) ^ l7) & 7) << 3);    // kc=1
    const int bsb = lg * 4;
    const int cvb = l15 * 32 + (((lg ^ (l15 >> 1)) & 3) << 3);  // paired CV

    // ---- register x-prefetch for it=0 (L3-resident: FETCH 34MB < x 64MB) ----
    float4 xr0, xr1, xr2, xr3;
    {
        const float* xrow = inputs + (size_t)(u * (NITER * 16) + l15) * 64;
        xr0 = *(const float4*)(xrow + lg * 8);
        xr1 = *(const float4*)(xrow + lg * 8 + 4);
        xr2 = *(const float4*)(xrow + 32 + lg * 8);
        xr3 = *(const float4*)(xrow + 32 + lg * 8 + 4);
    }

    #pragma unroll 1
    for (int it = 0; it < NITER; ++it) {
        const int row0 = u * (NITER * 16) + it * 16;
        const float* xrow = inputs + (size_t)(row0 + l15) * 64;   // rescue path

        // ---- limb-convert the prefetched x (native bf16 casts, r22) ----
        short8 xh[2], xl[2];
        #pragma unroll
        for (int kc = 0; kc < 2; ++kc) {
            float4 a = (kc == 0) ? xr0 : xr2;
            float4 b = (kc == 0) ? xr1 : xr3;
            float xv[8] = {a.x, a.y, a.z, a.w, b.x, b.y, b.z, b.w};
            bf16x8 h, l;
            #pragma unroll
            for (int e = 0; e < 8; ++e) {
                __bf16 hh = (__bf16)xv[e];
                h[e] = hh;
                l[e] = (__bf16)(xv[e] - (float)hh);
            }
            xh[kc] = __builtin_bit_cast(short8, h);
            xl[kc] = __builtin_bit_cast(short8, l);
        }

        f32x4 cv[4];
        #pragma unroll
        for (int dt = 0; dt < 4; ++dt) cv[dt] = (f32x4){0.f, 0.f, 0.f, 0.f};
        f32x4 sacc = (f32x4){0.f, 0.f, 0.f, 0.f};
        float m1A, m2A, m1B, m2B;
        int i1A, i1B, cA0, cA1, cA2, cB0, cB1, cB2;

        half_pass<0>(Wh, Wl, CVp, bs, xh, xl, l15, lg,
                     wb0, wb1, bsb, cvb,
                     cv, sacc, m1A, m2A, i1A, cA0, cA1, cA2);
        half_pass<160>(Wh, Wl, CVp, bs, xh, xl, l15, lg,
                       wb0, wb1, bsb, cvb,
                       cv, sacc, m1B, m2B, i1B, cB0, cB1, cB2);

        // ---- issue next-iter x prefetch (acc[] now dead -> no VGPR peak) ----
        if (it + 1 < NITER) {
            const float* xn = inputs + (size_t)(row0 + 16 + l15) * 64;
            xr0 = *(const float4*)(xn + lg * 8);
            xr1 = *(const float4*)(xn + lg * 8 + 4);
            xr2 = *(const float4*)(xn + 32 + lg * 8);
            xr3 = *(const float4*)(xn + 32 + lg * 8 + 4);
        }

        // ---- merge halves: global top-2 / argmax ----
        float m1 = m1A;
        int i1 = i1A;
        float m2 = fmaxf(fmaxf(m2A, m2B), fminf(m1A, m1B));
        if (m1B > m1) { m1 = m1B; i1 = i1B; }   // tie -> half A (smaller index)

        const float sum = sacc[0];   // MFMA K-reduce spans all 4 lane-groups

        // ---- exact-argmax rescue for near-ties (raw f32, nat units) ----
        // fmaf order (bias first, d ascending) preserved from r3-r22.
        const int mk = mask[u * NITER + it];   // wave-uniform
        int cw = i1;
        const bool flag = mk && (m1 - m2 < TAU2);
        if (__any(flag)) {
            float bv = -INFINITY;
            int bi = 0x7fffffff;
            #pragma unroll 1
            for (int t = 0; t < 8; ++t) {
                int c = (t == 0) ? i1A : (t == 1) ? i1B :
                        (t == 2) ? cA0 : (t == 3) ? cA1 : (t == 4) ? cA2 :
                        (t == 5) ? cB0 : (t == 6) ? cB1 : cB2;
                if (!flag) c = -1;
                if (__any(c >= 0)) {
                    if (c >= 0) {
                        float sacc2 = bcb[c];
                        #pragma unroll 4
                        for (int q = 0; q < 16; ++q) {
                            float4 xv4 = *(const float4*)(xrow + q * 4);
                            sacc2 = fmaf(xv4.x, Wcb[(q * 4 + 0) * 320 + c], sacc2);
                            sacc2 = fmaf(xv4.y, Wcb[(q * 4 + 1) * 320 + c], sacc2);
                            sacc2 = fmaf(xv4.z, Wcb[(q * 4 + 2) * 320 + c], sacc2);
                            sacc2 = fmaf(xv4.w, Wcb[(q * 4 + 3) * 320 + c], sacc2);
                        }
                        if (sacc2 > bv || (sacc2 == bv && c < bi)) { bv = sacc2; bi = c; }
                    }
                }
            }
            #pragma unroll
            for (int dx = 16; dx <= 32; dx <<= 1) {
                float vo = __shfl_xor(bv, dx, 64);
                int io = __shfl_xor(bi, dx, 64);
                if (vo > bv || (vo == bv && io < bi)) { bv = vo; bi = io; }
            }
            if (flag) cw = bi;
        }

        // ---- epilogue: mask, normalize, store ----
        const float inv = mk ? (1.0f / sum) : 0.0f;
        float* orow = out_cv + (size_t)(row0 + l15) * 64;
        #pragma unroll
        for (int dt = 0; dt < 4; ++dt) {
            f32x4 v;
            v[0] = cv[dt][0] * inv;
            v[1] = cv[dt][1] * inv;
            v[2] = cv[dt][2] * inv;
            v[3] = cv[dt][3] * inv;
            *(f32x4*)(orow + dt * 16 + lg * 4) = v;
        }
        if (lg == 0) out_cw[row0 + l15] = mk ? (float)cw : 0.0f;
    }
}

extern "C" void kernel_launch(void* const* d_in, const int* in_sizes, int n_in,
                              void* d_out, int out_size, void* d_ws, size_t ws_size,
                              hipStream_t stream) {
    const float* inputs  = (const float*)d_in[0];
    const int*   mask    = (const int*)d_in[1];
    const float* Wcb     = (const float*)d_in[2];
    const float* bcb     = (const float*)d_in[3];
    const float* codevec = (const float*)d_in[4];

    float* out_cv = (float*)d_out;
    float* out_cw = out_cv + (size_t)NROWS * 64;

    vq_mfma<<<GRID, BLOCK, 0, stream>>>(inputs, mask, Wcb, bcb, codevec,
                                        out_cv, out_cw);
}